// Round 11
// baseline (193.203 us; speedup 1.0000x reference)
//
#include <hip/hip_runtime.h>
#include <hip/hip_bf16.h>

typedef __attribute__((ext_vector_type(8))) short bf16x8;
typedef __attribute__((ext_vector_type(4))) float f32x4;

struct bf16x8_s { __hip_bfloat16 h[8]; };
struct bf16x4_s { __hip_bfloat16 h[4]; };

// ---------------- fp32 -> bf16 conversion (8 elems/thread) ----------------
__global__ void cvt_kernel(const float* __restrict__ in,
                           __hip_bfloat16* __restrict__ out, int n8) {
  int i = blockIdx.x * blockDim.x + threadIdx.x;
  if (i >= n8) return;
  const float4* p = reinterpret_cast<const float4*>(in) + (size_t)i * 2;
  float4 a = p[0], b = p[1];
  bf16x8_s o;
  o.h[0] = __float2bfloat16(a.x); o.h[1] = __float2bfloat16(a.y);
  o.h[2] = __float2bfloat16(a.z); o.h[3] = __float2bfloat16(a.w);
  o.h[4] = __float2bfloat16(b.x); o.h[5] = __float2bfloat16(b.y);
  o.h[6] = __float2bfloat16(b.z); o.h[7] = __float2bfloat16(b.w);
  *reinterpret_cast<bf16x8_s*>(out + (size_t)i * 8) = o;
}

__global__ void cvt4_kernel(const float* __restrict__ w0,
                            const float* __restrict__ w1,
                            const float* __restrict__ w2,
                            const float* __restrict__ w3,
                            __hip_bfloat16* __restrict__ out) {
  const int bid = blockIdx.x;
  const int seg = bid >> 9;
  const int i = (bid & 511) * 256 + threadIdx.x;
  const float* src = seg == 0 ? w0 : seg == 1 ? w1 : seg == 2 ? w2 : w3;
  const float4* p = reinterpret_cast<const float4*>(src) + (size_t)i * 2;
  float4 a = p[0], b = p[1];
  bf16x8_s o;
  o.h[0] = __float2bfloat16(a.x); o.h[1] = __float2bfloat16(a.y);
  o.h[2] = __float2bfloat16(a.z); o.h[3] = __float2bfloat16(a.w);
  o.h[4] = __float2bfloat16(b.x); o.h[5] = __float2bfloat16(b.y);
  o.h[6] = __float2bfloat16(b.z); o.h[7] = __float2bfloat16(b.w);
  *reinterpret_cast<bf16x8_s*>(out + (size_t)seg * 1048576 + (size_t)i * 8) = o;
}

// ---------------- 128x128 GEMM (m97 structure + T2 swizzle + coalesced epi) -
__device__ __forceinline__ void stage_tile(const __hip_bfloat16* src,
                                           char* lds, int tid) {
#pragma unroll
  for (int s = 0; s < 4; ++s) {
    const int c = s * 256 + tid;
    const int row = c >> 3;
    const int cb = (((c & 7) << 4) ^ ((row & 7) << 4));
    __builtin_amdgcn_global_load_lds(
        (const __attribute__((address_space(1))) void*)((const char*)(src + (size_t)row * 1024) + cb),
        (__attribute__((address_space(3))) void*)(lds + s * 4096 + (tid & 192) * 16),
        16, 0, 0);
  }
}

// MODE 0: fused QKV (tn 0..23; sel=tn>>3: Q scaled / K / V-transposed, bf16)
// MODE 1: projection (tn 0..7; fp32 out + bias)
template <int MODE>
__global__ __launch_bounds__(256) void gemm128(
    const __hip_bfloat16* __restrict__ A, const __hip_bfloat16* __restrict__ W,
    const float* __restrict__ b0, const float* __restrict__ b1,
    const float* __restrict__ b2, void* __restrict__ O0,
    void* __restrict__ O1, void* __restrict__ O2) {
  constexpr float SC = 0.18033688011112042f;  // 0.125 * log2(e)
  __shared__ char smem[32768];
  const int tid = threadIdx.x;
  const int lane = tid & 63;
  const int lrow = lane & 15;
  const int lhi = lane >> 4;
  const int wid = tid >> 6;
  const int wm = wid >> 1, wn = wid & 1;
  const int xr = (lrow & 7) << 4;

  const int n = blockIdx.x;
  const int wg = MODE == 0 ? (n & 7) * 192 + (n >> 3) : (n & 7) * 64 + (n >> 3);
  const int tm = wg & 63;
  const int tn = wg >> 6;
  const int row0 = tm * 128;

  const __hip_bfloat16* Ap = A + (size_t)row0 * 1024;
  const __hip_bfloat16* Wp = W + (size_t)(tn * 128) * 1024;

  f32x4 acc[4][4] = {};

  for (int k0 = 0; k0 < 1024; k0 += 64) {
    stage_tile(Ap + k0, smem, tid);
    stage_tile(Wp + k0, smem + 16384, tid);
    __syncthreads();
    bf16x8 af[4][2], bfr[4][2];
#pragma unroll
    for (int m = 0; m < 4; ++m) {
      const int ar = wm * 64 + m * 16 + lrow;
#pragma unroll
      for (int kk = 0; kk < 2; ++kk)
        af[m][kk] = *reinterpret_cast<const bf16x8*>(
            smem + ar * 128 + ((kk * 64 + lhi * 16) ^ xr));
    }
#pragma unroll
    for (int nn = 0; nn < 4; ++nn) {
      const int br = wn * 64 + nn * 16 + lrow;
#pragma unroll
      for (int kk = 0; kk < 2; ++kk)
        bfr[nn][kk] = *reinterpret_cast<const bf16x8*>(
            smem + 16384 + br * 128 + ((kk * 64 + lhi * 16) ^ xr));
    }
    __builtin_amdgcn_s_setprio(1);
#pragma unroll
    for (int kk = 0; kk < 2; ++kk)
#pragma unroll
      for (int m = 0; m < 4; ++m)
#pragma unroll
        for (int nn = 0; nn < 4; ++nn)
          acc[m][nn] = __builtin_amdgcn_mfma_f32_16x16x32_bf16(
              af[m][kk], bfr[nn][kk], acc[m][nn], 0, 0, 0);
    __builtin_amdgcn_s_setprio(0);
    __syncthreads();
  }

  // ---- epilogue: per-wave 8 KB LDS slice -> coalesced 16B stores
  char* epi = smem + wid * 8192;
  const int grow0 = row0 + wm * 64;

  if constexpr (MODE == 0) {
    const int sel = tn >> 3;
    const int cloc = (tn & 7) * 128 + wn * 64;
    const float* bias = sel == 0 ? b0 : sel == 1 ? b1 : b2;
    float bv4[4];
#pragma unroll
    for (int nn = 0; nn < 4; ++nn) bv4[nn] = bias[cloc + nn * 16 + lrow];

    if (sel != 2) {
      __hip_bfloat16* dst = sel == 0 ? (__hip_bfloat16*)O0 : (__hip_bfloat16*)O1;
#pragma unroll
      for (int mg = 0; mg < 4; ++mg) {
#pragma unroll
        for (int nn = 0; nn < 4; ++nn)
#pragma unroll
          for (int i = 0; i < 4; ++i) {
            float v = acc[mg][nn][i] + bv4[nn];
            if (sel == 0) v *= SC;
            ((__hip_bfloat16*)epi)[(lhi * 4 + i) * 72 + nn * 16 + lrow] =
                __float2bfloat16(v);
          }
#pragma unroll
        for (int ps = 0; ps < 2; ++ps) {
          const int r = ps * 8 + (lane >> 3);
          bf16x8 val = *reinterpret_cast<const bf16x8*>(epi + r * 144 + (lane & 7) * 16);
          const int grow = grow0 + mg * 16 + r;
          *reinterpret_cast<bf16x8*>(&dst[(size_t)grow * 1024 + cloc + (lane & 7) * 8]) = val;
        }
      }
    } else {
      __hip_bfloat16* dst = (__hip_bfloat16*)O2;
      const int h = cloc >> 6;
      const int bb = grow0 >> 11;
      const int t0 = grow0 & 2047;
      __hip_bfloat16* vb = dst + ((size_t)(bb * 16 + h) * 64) * 2048;
#pragma unroll
      for (int ng = 0; ng < 4; ++ng) {
#pragma unroll
        for (int m = 0; m < 4; ++m)
#pragma unroll
          for (int i = 0; i < 4; ++i) {
            const float v = acc[m][ng][i] + bv4[ng];
            ((__hip_bfloat16*)epi)[lrow * 72 + m * 16 + lhi * 4 + i] =
                __float2bfloat16(v);
          }
#pragma unroll
        for (int ps = 0; ps < 2; ++ps) {
          const int dr = ps * 8 + (lane >> 3);
          bf16x8 val = *reinterpret_cast<const bf16x8*>(epi + dr * 144 + (lane & 7) * 16);
          const int d = ng * 16 + dr;
          *reinterpret_cast<bf16x8*>(&vb[(size_t)d * 2048 + t0 + (lane & 7) * 8]) = val;
        }
      }
    }
  } else {
    float* dst = (float*)O0;
    const int cloc = tn * 128 + wn * 64;
    float bv4[4];
#pragma unroll
    for (int nn = 0; nn < 4; ++nn) bv4[nn] = b0[cloc + nn * 16 + lrow];
#pragma unroll
    for (int mg = 0; mg < 4; ++mg) {
#pragma unroll
      for (int nn = 0; nn < 4; ++nn)
#pragma unroll
        for (int i = 0; i < 4; ++i)
          ((float*)epi)[(lhi * 4 + i) * 68 + nn * 16 + lrow] =
              acc[mg][nn][i] + bv4[nn];
#pragma unroll
      for (int ps = 0; ps < 4; ++ps) {
        const int r = ps * 4 + (lane >> 4);
        float4 val = *reinterpret_cast<const float4*>(epi + r * 272 + (lane & 15) * 16);
        const int grow = grow0 + mg * 16 + r;
        *reinterpret_cast<float4*>(&dst[(size_t)grow * 1024 + cloc + (lane & 15) * 4]) = val;
      }
    }
  }
}

// ---------------- flash attention: paired tiles, counted-vmcnt rounds ------
// Block = 4 waves; each wave owns 32 q-rows of tile A (heavy) and tile B
// (light), qtA+qtB=15 -> uniform ~33 wave-steps/block; 512 blocks = 2/CU.
// Round t: { s_barrier; stage(t+1); vmcnt(4) [= stage(t) landed]; compute }.
// Never drains vmcnt to 0 mid-loop (T4): stage latency hides under compute.
// Dual step shares each kf/vf ds_read across both tiles (4 MFMAs per read).
__device__ __forceinline__ void stage_kv(char* __restrict__ smem, int buf,
                                         const __hip_bfloat16* __restrict__ Kb,
                                         const __hip_bfloat16* __restrict__ Vb,
                                         int kv0, int tid) {
  const int w = tid >> 6, l = tid & 63;
  char* base = smem + buf * 16384;
#pragma unroll
  for (int s = 0; s < 2; ++s) {
    const int c = s * 256 + w * 64 + l;
    const int row = c >> 3;
    const int scb = ((c & 7) << 4) ^ ((row & 7) << 4);
    __builtin_amdgcn_global_load_lds(
        (const __attribute__((address_space(1))) void*)(Kb + (size_t)(kv0 + row) * 1024 + (scb >> 1)),
        (__attribute__((address_space(3))) void*)(base + s * 4096 + w * 1024), 16, 0, 0);
  }
#pragma unroll
  for (int s = 0; s < 2; ++s) {
    const int c = s * 256 + w * 64 + l;
    const int row = c >> 3;
    const int scb = ((c & 7) << 4) ^ ((row & 7) << 4);
    __builtin_amdgcn_global_load_lds(
        (const __attribute__((address_space(1))) void*)(Vb + (size_t)row * 2048 + kv0 + (scb >> 1)),
        (__attribute__((address_space(3))) void*)(base + 8192 + s * 4096 + w * 1024), 16, 0, 0);
  }
}

// softmax for one tile: s -> P(LDS) -> pf fragments; updates m,l,o-rescale
__device__ __forceinline__ void softmax_tile(
    f32x4 s[2][4], bool masked, int kv0, int q0w, int lrow, int lhi,
    f32x4 o[2][4], float m[2], float l[2], __hip_bfloat16* __restrict__ P,
    bf16x8 pf[2][2]) {
  constexpr float TH = 8.0f;
  if (masked) {
#pragma unroll
    for (int j = 0; j < 2; ++j)
#pragma unroll
      for (int g = 0; g < 4; ++g)
#pragma unroll
        for (int i = 0; i < 4; ++i) {
          const int k = kv0 + g * 16 + lhi * 4 + i;
          if (k > q0w + j * 16 + lrow) s[j][g][i] = -1e30f;
        }
  }
  float mx[2];
#pragma unroll
  for (int j = 0; j < 2; ++j) {
    float gm[4];
#pragma unroll
    for (int g = 0; g < 4; ++g)
      gm[g] = fmaxf(fmaxf(s[j][g][0], s[j][g][1]), fmaxf(s[j][g][2], s[j][g][3]));
    float t = fmaxf(fmaxf(gm[0], gm[1]), fmaxf(gm[2], gm[3]));
    t = fmaxf(t, __shfl_xor(t, 16));
    t = fmaxf(t, __shfl_xor(t, 32));
    mx[j] = t;
  }
  const int need = (mx[0] > m[0] + TH) || (mx[1] > m[1] + TH);
  if (__any(need)) {
#pragma unroll
    for (int j = 0; j < 2; ++j) {
      const float nm = fmaxf(m[j], mx[j]);
      const float al = exp2f(m[j] - nm);
      m[j] = nm;
      l[j] *= al;
      float a4[4];
#pragma unroll
      for (int i = 0; i < 4; ++i) a4[i] = __shfl(al, 4 * lhi + i, 16);
#pragma unroll
      for (int f = 0; f < 4; ++f)
#pragma unroll
        for (int i = 0; i < 4; ++i) o[j][f][i] *= a4[i];
    }
  }
#pragma unroll
  for (int j = 0; j < 2; ++j) {
    float gs[4];
#pragma unroll
    for (int g = 0; g < 4; ++g) {
      bf16x4_s t4;
      float p0 = exp2f(s[j][g][0] - m[j]);
      float p1 = exp2f(s[j][g][1] - m[j]);
      float p2 = exp2f(s[j][g][2] - m[j]);
      float p3 = exp2f(s[j][g][3] - m[j]);
      t4.h[0] = __float2bfloat16(p0); t4.h[1] = __float2bfloat16(p1);
      t4.h[2] = __float2bfloat16(p2); t4.h[3] = __float2bfloat16(p3);
      gs[g] = (p0 + p1) + (p2 + p3);
      *reinterpret_cast<bf16x4_s*>(P + (j * 16 + lrow) * 72 + g * 16 + lhi * 4) = t4;
    }
    float sum = (gs[0] + gs[1]) + (gs[2] + gs[3]);
    sum += __shfl_xor(sum, 16);
    sum += __shfl_xor(sum, 32);
    l[j] += sum;
#pragma unroll
    for (int nn = 0; nn < 2; ++nn)
      pf[j][nn] = *reinterpret_cast<const bf16x8*>(
          P + (j * 16 + lrow) * 72 + nn * 32 + lhi * 8);
  }
}

// dual-tile step: shared kf/vf ds_reads feed both tiles' MFMAs
template <bool DOB>
__device__ __forceinline__ void attn_step2(
    int kv0, int q0A, int q0B, bool mA, bool mB, int lrow, int lhi,
    const char* __restrict__ kvb, const bf16x8 qfA[2][2],
    const bf16x8 qfB[2][2], f32x4 oA[2][4], f32x4 oB[2][4], float mAr[2],
    float lAr[2], float mBr[2], float lBr[2], __hip_bfloat16* __restrict__ P) {
  const int xr = (lrow & 7) << 4;
  f32x4 sA[2][4] = {}, sB[2][4] = {};
  __builtin_amdgcn_s_setprio(1);
#pragma unroll
  for (int g = 0; g < 4; ++g) {
    const char* rowp = kvb + (g * 16 + lrow) * 128;
#pragma unroll
    for (int kk = 0; kk < 2; ++kk) {
      bf16x8 kf = *reinterpret_cast<const bf16x8*>(rowp + ((kk * 64 + lhi * 16) ^ xr));
      sA[0][g] = __builtin_amdgcn_mfma_f32_16x16x32_bf16(kf, qfA[0][kk], sA[0][g], 0, 0, 0);
      sA[1][g] = __builtin_amdgcn_mfma_f32_16x16x32_bf16(kf, qfA[1][kk], sA[1][g], 0, 0, 0);
      if (DOB) {
        sB[0][g] = __builtin_amdgcn_mfma_f32_16x16x32_bf16(kf, qfB[0][kk], sB[0][g], 0, 0, 0);
        sB[1][g] = __builtin_amdgcn_mfma_f32_16x16x32_bf16(kf, qfB[1][kk], sB[1][g], 0, 0, 0);
      }
    }
  }
  __builtin_amdgcn_s_setprio(0);
  bf16x8 pfA[2][2], pfB[2][2];
  softmax_tile(sA, mA, kv0, q0A, lrow, lhi, oA, mAr, lAr, P, pfA);
  if (DOB) softmax_tile(sB, mB, kv0, q0B, lrow, lhi, oB, mBr, lBr, P, pfB);
  __builtin_amdgcn_s_setprio(1);
#pragma unroll
  for (int nn = 0; nn < 2; ++nn)
#pragma unroll
    for (int f = 0; f < 4; ++f) {
      bf16x8 vf = *reinterpret_cast<const bf16x8*>(
          kvb + 8192 + (f * 16 + lrow) * 128 + ((nn * 64 + lhi * 16) ^ xr));
      oA[0][f] = __builtin_amdgcn_mfma_f32_16x16x32_bf16(pfA[0][nn], vf, oA[0][f], 0, 0, 0);
      oA[1][f] = __builtin_amdgcn_mfma_f32_16x16x32_bf16(pfA[1][nn], vf, oA[1][f], 0, 0, 0);
      if (DOB) {
        oB[0][f] = __builtin_amdgcn_mfma_f32_16x16x32_bf16(pfB[0][nn], vf, oB[0][f], 0, 0, 0);
        oB[1][f] = __builtin_amdgcn_mfma_f32_16x16x32_bf16(pfB[1][nn], vf, oB[1][f], 0, 0, 0);
      }
    }
  __builtin_amdgcn_s_setprio(0);
}

__global__ __launch_bounds__(256, 2) void attn_fwd(
    const __hip_bfloat16* __restrict__ Q, const __hip_bfloat16* __restrict__ Km,
    const __hip_bfloat16* __restrict__ Vt, __hip_bfloat16* __restrict__ Y) {
  constexpr int T = 2048, C = 1024, D = 64;
  const int tid = threadIdx.x;
  const int wid = tid >> 6;
  const int lane = tid & 63;
  const int lrow = lane & 15;
  const int lhi = lane >> 4;
  const int n = blockIdx.x;
  const int xcd = n & 7;
  const int w8 = n >> 3;                 // 0..63
  const int bh = xcd * 8 + (w8 & 7);
  const int pr = w8 >> 3;                // 0..7
  const int qtA = 15 - pr;               // heavy tile
  const int qtB = pr;                    // light tile
  const int b = bh >> 4, h = bh & 15;
  const int q0A = qtA * 128 + wid * 32;
  const int q0B = qtB * 128 + wid * 32;

  const __hip_bfloat16* Qb = Q + ((size_t)b * T) * C + h * D;
  const __hip_bfloat16* Kb = Km + ((size_t)b * T) * C + h * D;
  const __hip_bfloat16* Vb = Vt + (size_t)bh * D * T;

  __shared__ char smem[51200];
  __hip_bfloat16* P = (__hip_bfloat16*)(smem + 32768 + wid * 4608);

  bf16x8 qfA[2][2], qfB[2][2];
#pragma unroll
  for (int j = 0; j < 2; ++j)
#pragma unroll
    for (int kk = 0; kk < 2; ++kk) {
      qfA[j][kk] = *reinterpret_cast<const bf16x8*>(
          Qb + (size_t)(q0A + j * 16 + lrow) * C + kk * 32 + lhi * 8);
      qfB[j][kk] = *reinterpret_cast<const bf16x8*>(
          Qb + (size_t)(q0B + j * 16 + lrow) * C + kk * 32 + lhi * 8);
    }

  f32x4 oA[2][4] = {}, oB[2][4] = {};
  float mA[2] = {-1e30f, -1e30f}, lA[2] = {0.f, 0.f};
  float mB[2] = {-1e30f, -1e30f}, lB[2] = {0.f, 0.f};

  const int nt = 2 * qtA + 2;           // stream length (heavy tile)
  const int nsA = (q0A >> 6) + 1;
  const int nsB = (q0B >> 6) + 1;

  stage_kv(smem, 0, Kb, Vb, 0, tid);
  for (int t = 0; t < nt; ++t) {
    // all waves done reading buf[(t-1)&1] -> safe for stage(t+1) to overwrite
    __builtin_amdgcn_s_barrier();
    __builtin_amdgcn_sched_barrier(0);
    if (t + 1 < nt) {
      stage_kv(smem, (t + 1) & 1, Kb, Vb, (t + 1) * 64, tid);
      asm volatile("s_waitcnt vmcnt(4)" ::: "memory");  // stage(t) landed
    } else {
      asm volatile("s_waitcnt vmcnt(0)" ::: "memory");
    }
    __builtin_amdgcn_sched_barrier(0);
    const char* kvb = smem + (t & 1) * 16384;
    if (t < nsA) {
      const bool mAq = (t == nsA - 1);
      if (t < nsB)
        attn_step2<true>(t * 64, q0A, q0B, mAq, t == nsB - 1, lrow, lhi, kvb,
                         qfA, qfB, oA, oB, mA, lA, mB, lB, P);
      else
        attn_step2<false>(t * 64, q0A, q0B, mAq, false, lrow, lhi, kvb, qfA,
                          qfB, oA, oB, mA, lA, mB, lB, P);
    }
  }

  // ---- normalize + store (both tiles)
#pragma unroll
  for (int j = 0; j < 2; ++j) {
    float l4[4];
#pragma unroll
    for (int i = 0; i < 4; ++i) l4[i] = __shfl(lA[j], 4 * lhi + i, 16);
#pragma unroll
    for (int f = 0; f < 4; ++f)
#pragma unroll
      for (int i = 0; i < 4; ++i) {
        const int row = q0A + j * 16 + 4 * lhi + i;
        Y[((size_t)b * T + row) * C + h * D + f * 16 + lrow] =
            __float2bfloat16(oA[j][f][i] / l4[i]);
      }
  }
#pragma unroll
  for (int j = 0; j < 2; ++j) {
    float l4[4];
#pragma unroll
    for (int i = 0; i < 4; ++i) l4[i] = __shfl(lB[j], 4 * lhi + i, 16);
#pragma unroll
    for (int f = 0; f < 4; ++f)
#pragma unroll
      for (int i = 0; i < 4; ++i) {
        const int row = q0B + j * 16 + 4 * lhi + i;
        Y[((size_t)b * T + row) * C + h * D + f * 16 + lrow] =
            __float2bfloat16(oB[j][f][i] / l4[i]);
      }
  }
}

// ---------------- host launch ----------------------------------------------
extern "C" void kernel_launch(void* const* d_in, const int* in_sizes, int n_in,
                              void* d_out, int out_size, void* d_ws,
                              size_t ws_size, hipStream_t stream) {
  const float* x = (const float*)d_in[0];
  const float* Wq = (const float*)d_in[1];
  const float* bq = (const float*)d_in[2];
  const float* Wk = (const float*)d_in[3];
  const float* bk = (const float*)d_in[4];
  const float* Wv = (const float*)d_in[5];
  const float* bv = (const float*)d_in[6];
  const float* Wp = (const float*)d_in[7];
  const float* bp = (const float*)d_in[8];
  float* out = (float*)d_out;

  __hip_bfloat16* ws = (__hip_bfloat16*)d_ws;
  __hip_bfloat16* xb = ws;                   // 8388608
  __hip_bfloat16* wqb = xb + 8388608;        // 4 x 1048576, contiguous
  __hip_bfloat16* wpb = wqb + 3 * 1048576;
  __hip_bfloat16* Qs = wqb + 4 * 1048576;    // 8388608
  __hip_bfloat16* Ks = Qs + 8388608;
  __hip_bfloat16* Vts = Ks + 8388608;        // V^T: [B*H*64][2048]
  __hip_bfloat16* Ys = Vts + 8388608;        // attn out [B*T][C]

  cvt_kernel<<<4096, 256, 0, stream>>>(x, xb, 1048576);
  cvt4_kernel<<<2048, 256, 0, stream>>>(Wq, Wk, Wv, Wp, wqb);

  gemm128<0><<<dim3(1536), 256, 0, stream>>>(xb, wqb, bq, bk, bv, Qs, Ks, Vts);

  attn_fwd<<<dim3(512), 256, 0, stream>>>(Qs, Ks, Vts, Ys);

  gemm128<1><<<dim3(512), 256, 0, stream>>>(Ys, wpb, bp, nullptr, nullptr, out,
                                            nullptr, nullptr);
}

// Round 12
// 182.170 us; speedup vs baseline: 1.0606x; 1.0606x over previous
//
#include <hip/hip_runtime.h>
#include <hip/hip_bf16.h>

typedef __attribute__((ext_vector_type(8))) short bf16x8;
typedef __attribute__((ext_vector_type(4))) float f32x4;

struct bf16x8_s { __hip_bfloat16 h[8]; };
struct bf16x4_s { __hip_bfloat16 h[4]; };

// ---------------- fp32 -> bf16 conversion (8 elems/thread) ----------------
__global__ void cvt_kernel(const float* __restrict__ in,
                           __hip_bfloat16* __restrict__ out, int n8) {
  int i = blockIdx.x * blockDim.x + threadIdx.x;
  if (i >= n8) return;
  const float4* p = reinterpret_cast<const float4*>(in) + (size_t)i * 2;
  float4 a = p[0], b = p[1];
  bf16x8_s o;
  o.h[0] = __float2bfloat16(a.x); o.h[1] = __float2bfloat16(a.y);
  o.h[2] = __float2bfloat16(a.z); o.h[3] = __float2bfloat16(a.w);
  o.h[4] = __float2bfloat16(b.x); o.h[5] = __float2bfloat16(b.y);
  o.h[6] = __float2bfloat16(b.z); o.h[7] = __float2bfloat16(b.w);
  *reinterpret_cast<bf16x8_s*>(out + (size_t)i * 8) = o;
}

__global__ void cvt4_kernel(const float* __restrict__ w0,
                            const float* __restrict__ w1,
                            const float* __restrict__ w2,
                            const float* __restrict__ w3,
                            __hip_bfloat16* __restrict__ out) {
  const int bid = blockIdx.x;
  const int seg = bid >> 9;
  const int i = (bid & 511) * 256 + threadIdx.x;
  const float* src = seg == 0 ? w0 : seg == 1 ? w1 : seg == 2 ? w2 : w3;
  const float4* p = reinterpret_cast<const float4*>(src) + (size_t)i * 2;
  float4 a = p[0], b = p[1];
  bf16x8_s o;
  o.h[0] = __float2bfloat16(a.x); o.h[1] = __float2bfloat16(a.y);
  o.h[2] = __float2bfloat16(a.z); o.h[3] = __float2bfloat16(a.w);
  o.h[4] = __float2bfloat16(b.x); o.h[5] = __float2bfloat16(b.y);
  o.h[6] = __float2bfloat16(b.z); o.h[7] = __float2bfloat16(b.w);
  *reinterpret_cast<bf16x8_s*>(out + (size_t)seg * 1048576 + (size_t)i * 8) = o;
}

// ---------------- 128x128 GEMM (m97 structure + T2 swizzle + coalesced epi) -
__device__ __forceinline__ void stage_tile(const __hip_bfloat16* src,
                                           char* lds, int tid) {
#pragma unroll
  for (int s = 0; s < 4; ++s) {
    const int c = s * 256 + tid;
    const int row = c >> 3;
    const int cb = (((c & 7) << 4) ^ ((row & 7) << 4));
    __builtin_amdgcn_global_load_lds(
        (const __attribute__((address_space(1))) void*)((const char*)(src + (size_t)row * 1024) + cb),
        (__attribute__((address_space(3))) void*)(lds + s * 4096 + (tid & 192) * 16),
        16, 0, 0);
  }
}

// MODE 0: fused QKV (tn 0..23; sel=tn>>3: Q scaled / K / V-transposed, bf16)
// MODE 1: projection (tn 0..7; fp32 out + bias)
template <int MODE>
__global__ __launch_bounds__(256) void gemm128(
    const __hip_bfloat16* __restrict__ A, const __hip_bfloat16* __restrict__ W,
    const float* __restrict__ b0, const float* __restrict__ b1,
    const float* __restrict__ b2, void* __restrict__ O0,
    void* __restrict__ O1, void* __restrict__ O2) {
  constexpr float SC = 0.18033688011112042f;  // 0.125 * log2(e)
  __shared__ char smem[32768];
  const int tid = threadIdx.x;
  const int lane = tid & 63;
  const int lrow = lane & 15;
  const int lhi = lane >> 4;
  const int wid = tid >> 6;
  const int wm = wid >> 1, wn = wid & 1;
  const int xr = (lrow & 7) << 4;

  const int n = blockIdx.x;
  const int wg = MODE == 0 ? (n & 7) * 192 + (n >> 3) : (n & 7) * 64 + (n >> 3);
  const int tm = wg & 63;
  const int tn = wg >> 6;
  const int row0 = tm * 128;

  const __hip_bfloat16* Ap = A + (size_t)row0 * 1024;
  const __hip_bfloat16* Wp = W + (size_t)(tn * 128) * 1024;

  f32x4 acc[4][4] = {};

  for (int k0 = 0; k0 < 1024; k0 += 64) {
    stage_tile(Ap + k0, smem, tid);
    stage_tile(Wp + k0, smem + 16384, tid);
    __syncthreads();
    bf16x8 af[4][2], bfr[4][2];
#pragma unroll
    for (int m = 0; m < 4; ++m) {
      const int ar = wm * 64 + m * 16 + lrow;
#pragma unroll
      for (int kk = 0; kk < 2; ++kk)
        af[m][kk] = *reinterpret_cast<const bf16x8*>(
            smem + ar * 128 + ((kk * 64 + lhi * 16) ^ xr));
    }
#pragma unroll
    for (int nn = 0; nn < 4; ++nn) {
      const int br = wn * 64 + nn * 16 + lrow;
#pragma unroll
      for (int kk = 0; kk < 2; ++kk)
        bfr[nn][kk] = *reinterpret_cast<const bf16x8*>(
            smem + 16384 + br * 128 + ((kk * 64 + lhi * 16) ^ xr));
    }
    __builtin_amdgcn_s_setprio(1);
#pragma unroll
    for (int kk = 0; kk < 2; ++kk)
#pragma unroll
      for (int m = 0; m < 4; ++m)
#pragma unroll
        for (int nn = 0; nn < 4; ++nn)
          acc[m][nn] = __builtin_amdgcn_mfma_f32_16x16x32_bf16(
              af[m][kk], bfr[nn][kk], acc[m][nn], 0, 0, 0);
    __builtin_amdgcn_s_setprio(0);
    __syncthreads();
  }

  // ---- epilogue: per-wave 8 KB LDS slice -> coalesced 16B stores
  char* epi = smem + wid * 8192;
  const int grow0 = row0 + wm * 64;

  if constexpr (MODE == 0) {
    const int sel = tn >> 3;
    const int cloc = (tn & 7) * 128 + wn * 64;
    const float* bias = sel == 0 ? b0 : sel == 1 ? b1 : b2;
    float bv4[4];
#pragma unroll
    for (int nn = 0; nn < 4; ++nn) bv4[nn] = bias[cloc + nn * 16 + lrow];

    if (sel != 2) {
      __hip_bfloat16* dst = sel == 0 ? (__hip_bfloat16*)O0 : (__hip_bfloat16*)O1;
#pragma unroll
      for (int mg = 0; mg < 4; ++mg) {
#pragma unroll
        for (int nn = 0; nn < 4; ++nn)
#pragma unroll
          for (int i = 0; i < 4; ++i) {
            float v = acc[mg][nn][i] + bv4[nn];
            if (sel == 0) v *= SC;
            ((__hip_bfloat16*)epi)[(lhi * 4 + i) * 72 + nn * 16 + lrow] =
                __float2bfloat16(v);
          }
#pragma unroll
        for (int ps = 0; ps < 2; ++ps) {
          const int r = ps * 8 + (lane >> 3);
          bf16x8 val = *reinterpret_cast<const bf16x8*>(epi + r * 144 + (lane & 7) * 16);
          const int grow = grow0 + mg * 16 + r;
          *reinterpret_cast<bf16x8*>(&dst[(size_t)grow * 1024 + cloc + (lane & 7) * 8]) = val;
        }
      }
    } else {
      __hip_bfloat16* dst = (__hip_bfloat16*)O2;
      const int h = cloc >> 6;
      const int bb = grow0 >> 11;
      const int t0 = grow0 & 2047;
      __hip_bfloat16* vb = dst + ((size_t)(bb * 16 + h) * 64) * 2048;
#pragma unroll
      for (int ng = 0; ng < 4; ++ng) {
#pragma unroll
        for (int m = 0; m < 4; ++m)
#pragma unroll
          for (int i = 0; i < 4; ++i) {
            const float v = acc[m][ng][i] + bv4[ng];
            ((__hip_bfloat16*)epi)[lrow * 72 + m * 16 + lhi * 4 + i] =
                __float2bfloat16(v);
          }
#pragma unroll
        for (int ps = 0; ps < 2; ++ps) {
          const int dr = ps * 8 + (lane >> 3);
          bf16x8 val = *reinterpret_cast<const bf16x8*>(epi + dr * 144 + (lane & 7) * 16);
          const int d = ng * 16 + dr;
          *reinterpret_cast<bf16x8*>(&vb[(size_t)d * 2048 + t0 + (lane & 7) * 8]) = val;
        }
      }
    }
  } else {
    float* dst = (float*)O0;
    const int cloc = tn * 128 + wn * 64;
    float bv4[4];
#pragma unroll
    for (int nn = 0; nn < 4; ++nn) bv4[nn] = b0[cloc + nn * 16 + lrow];
#pragma unroll
    for (int mg = 0; mg < 4; ++mg) {
#pragma unroll
      for (int nn = 0; nn < 4; ++nn)
#pragma unroll
        for (int i = 0; i < 4; ++i)
          ((float*)epi)[(lhi * 4 + i) * 68 + nn * 16 + lrow] =
              acc[mg][nn][i] + bv4[nn];
#pragma unroll
      for (int ps = 0; ps < 4; ++ps) {
        const int r = ps * 4 + (lane >> 4);
        float4 val = *reinterpret_cast<const float4*>(epi + r * 272 + (lane & 15) * 16);
        const int grow = grow0 + mg * 16 + r;
        *reinterpret_cast<float4*>(&dst[(size_t)grow * 1024 + cloc + (lane & 15) * 4]) = val;
      }
    }
  }
}

// ---------------- flash attention: 64-row tiles, backfill packing ----------
// Block = 4 waves x 16 q-rows = one 64-row q-tile; nt = qt+1 rounds -> a
// block streams exactly what it computes (no idle staging rounds). 2048
// blocks, heavy-first (LPT) + XCD-bh grouping; 40960 B LDS -> 4 blocks/CU
// (16 waves/CU). K/V double-buffered via global_load_lds (linear dest,
// inverse-XOR source; reads re-apply XOR). P: 2 KB/wave, XOR-swizzled
// stride-64 (<=2-way banks). Proven R9 sync rotation: sync drains stage(t)
// issued last round; stage(t+1); compute(t).
__device__ __forceinline__ void stage_kv(char* __restrict__ smem, int buf,
                                         const __hip_bfloat16* __restrict__ Kb,
                                         const __hip_bfloat16* __restrict__ Vb,
                                         int kv0, int tid) {
  const int w = tid >> 6, l = tid & 63;
  char* base = smem + buf * 16384;
#pragma unroll
  for (int s = 0; s < 2; ++s) {
    const int c = s * 256 + w * 64 + l;
    const int row = c >> 3;
    const int scb = ((c & 7) << 4) ^ ((row & 7) << 4);
    __builtin_amdgcn_global_load_lds(
        (const __attribute__((address_space(1))) void*)(Kb + (size_t)(kv0 + row) * 1024 + (scb >> 1)),
        (__attribute__((address_space(3))) void*)(base + s * 4096 + w * 1024), 16, 0, 0);
  }
#pragma unroll
  for (int s = 0; s < 2; ++s) {
    const int c = s * 256 + w * 64 + l;
    const int row = c >> 3;
    const int scb = ((c & 7) << 4) ^ ((row & 7) << 4);
    __builtin_amdgcn_global_load_lds(
        (const __attribute__((address_space(1))) void*)(Vb + (size_t)row * 2048 + kv0 + (scb >> 1)),
        (__attribute__((address_space(3))) void*)(base + 8192 + s * 4096 + w * 1024), 16, 0, 0);
  }
}

template <bool MASKED>
__device__ __forceinline__ void attn_step(
    int kv0, int q0, int lrow, int lhi, const char* __restrict__ kvb,
    const bf16x8 qf[2], f32x4 o[4], float& m, float& l,
    char* __restrict__ Pw) {
  constexpr float TH = 8.0f;
  const int xr = (lrow & 7) << 4;
  // ---- S^T = K @ Q^T from swizzled LDS
  f32x4 s[4] = {};
  __builtin_amdgcn_s_setprio(1);
#pragma unroll
  for (int g = 0; g < 4; ++g) {
    const char* rowp = kvb + (g * 16 + lrow) * 128;
#pragma unroll
    for (int kk = 0; kk < 2; ++kk) {
      bf16x8 kf = *reinterpret_cast<const bf16x8*>(rowp + ((kk * 64 + lhi * 16) ^ xr));
      s[g] = __builtin_amdgcn_mfma_f32_16x16x32_bf16(kf, qf[kk], s[g], 0, 0, 0);
    }
  }
  __builtin_amdgcn_s_setprio(0);
  // ---- mask + balanced-tree row max
  if (MASKED) {
#pragma unroll
    for (int g = 0; g < 4; ++g)
#pragma unroll
      for (int i = 0; i < 4; ++i) {
        const int k = kv0 + g * 16 + lhi * 4 + i;
        if (k > q0 + lrow) s[g][i] = -1e30f;
      }
  }
  float gm[4];
#pragma unroll
  for (int g = 0; g < 4; ++g)
    gm[g] = fmaxf(fmaxf(s[g][0], s[g][1]), fmaxf(s[g][2], s[g][3]));
  float mx = fmaxf(fmaxf(gm[0], gm[1]), fmaxf(gm[2], gm[3]));
  mx = fmaxf(mx, __shfl_xor(mx, 16));
  mx = fmaxf(mx, __shfl_xor(mx, 32));
  // ---- T13 defer-max
  if (__any(mx > m + TH)) {
    const float nm = fmaxf(m, mx);
    const float al = exp2f(m - nm);
    m = nm;
    l *= al;
    float a4[4];
#pragma unroll
    for (int i = 0; i < 4; ++i) a4[i] = __shfl(al, 4 * lhi + i, 16);
#pragma unroll
    for (int f = 0; f < 4; ++f)
#pragma unroll
      for (int i = 0; i < 4; ++i) o[f][i] *= a4[i];
  }
  // ---- P = exp2(s - m) -> swizzled per-wave LDS (stride 64, 2-way banks)
  float gs[4];
#pragma unroll
  for (int g = 0; g < 4; ++g) {
    bf16x4_s t4;
    float p0 = exp2f(s[g][0] - m);
    float p1 = exp2f(s[g][1] - m);
    float p2 = exp2f(s[g][2] - m);
    float p3 = exp2f(s[g][3] - m);
    t4.h[0] = __float2bfloat16(p0); t4.h[1] = __float2bfloat16(p1);
    t4.h[2] = __float2bfloat16(p2); t4.h[3] = __float2bfloat16(p3);
    gs[g] = (p0 + p1) + (p2 + p3);
    *reinterpret_cast<bf16x4_s*>(Pw + lrow * 128 + ((g * 32 + lhi * 8) ^ xr)) = t4;
  }
  float sum = (gs[0] + gs[1]) + (gs[2] + gs[3]);
  sum += __shfl_xor(sum, 16);
  sum += __shfl_xor(sum, 32);
  l += sum;
  // ---- read P as A-fragments, O += P V
  bf16x8 pf[2];
#pragma unroll
  for (int nn = 0; nn < 2; ++nn)
    pf[nn] = *reinterpret_cast<const bf16x8*>(
        Pw + lrow * 128 + ((nn * 64 + lhi * 16) ^ xr));
  __builtin_amdgcn_s_setprio(1);
#pragma unroll
  for (int nn = 0; nn < 2; ++nn)
#pragma unroll
    for (int f = 0; f < 4; ++f) {
      bf16x8 vf = *reinterpret_cast<const bf16x8*>(
          kvb + 8192 + (f * 16 + lrow) * 128 + ((nn * 64 + lhi * 16) ^ xr));
      o[f] = __builtin_amdgcn_mfma_f32_16x16x32_bf16(pf[nn], vf, o[f], 0, 0, 0);
    }
  __builtin_amdgcn_s_setprio(0);
}

__global__ __launch_bounds__(256, 4) void attn_fwd(
    const __hip_bfloat16* __restrict__ Q, const __hip_bfloat16* __restrict__ Km,
    const __hip_bfloat16* __restrict__ Vt, __hip_bfloat16* __restrict__ Y) {
  constexpr int T = 2048, C = 1024, D = 64;
  const int tid = threadIdx.x;
  const int wid = tid >> 6;
  const int lane = tid & 63;
  const int lrow = lane & 15;
  const int lhi = lane >> 4;
  // 2048 blocks: XCD = n&7 owns a bh group; qt heavy-first (LPT backfill).
  const int n = blockIdx.x;
  const int xcd = n & 7;
  const int w8 = n >> 3;                 // 0..255
  const int bh = xcd * 8 + (w8 & 7);
  const int qt = 31 - (w8 >> 3);         // 0..31, heavy dispatched first
  const int b = bh >> 4, h = bh & 15;
  const int q0 = qt * 64 + wid * 16;     // this wave's 16 q-rows

  const __hip_bfloat16* Qb = Q + ((size_t)b * T) * C + h * D;
  const __hip_bfloat16* Kb = Km + ((size_t)b * T) * C + h * D;
  const __hip_bfloat16* Vb = Vt + (size_t)bh * D * T;

  // LDS: KV 2x16KB dbuf + per-wave P 4 x 2KB = 40960 -> 4 blocks/CU.
  __shared__ char smem[40960];
  char* Pw = smem + 32768 + wid * 2048;

  bf16x8 qf[2];
#pragma unroll
  for (int kk = 0; kk < 2; ++kk)
    qf[kk] = *reinterpret_cast<const bf16x8*>(
        Qb + (size_t)(q0 + lrow) * C + kk * 32 + lhi * 8);

  f32x4 o[4] = {};
  float m = -1e30f, l = 0.f;

  const int nt = qt + 1;  // rounds == compute steps (uniform across waves)

  stage_kv(smem, 0, Kb, Vb, 0, tid);
  for (int t = 0; t < nt; ++t) {
    __syncthreads();  // drains stage(t) issued last round; retires t-1 reads
    if (t + 1 < nt) stage_kv(smem, (t + 1) & 1, Kb, Vb, (t + 1) * 64, tid);
    const char* kvb = smem + (t & 1) * 16384;
    if (t == nt - 1)
      attn_step<true>(t * 64, q0, lrow, lhi, kvb, qf, o, m, l, Pw);
    else
      attn_step<false>(t * 64, q0, lrow, lhi, kvb, qf, o, m, l, Pw);
  }

  // ---- normalize + store
  float l4[4];
#pragma unroll
  for (int i = 0; i < 4; ++i) l4[i] = __shfl(l, 4 * lhi + i, 16);
#pragma unroll
  for (int f = 0; f < 4; ++f)
#pragma unroll
    for (int i = 0; i < 4; ++i) {
      const int row = q0 + 4 * lhi + i;
      Y[((size_t)b * T + row) * C + h * D + f * 16 + lrow] =
          __float2bfloat16(o[f][i] / l4[i]);
    }
}

// ---------------- host launch ----------------------------------------------
extern "C" void kernel_launch(void* const* d_in, const int* in_sizes, int n_in,
                              void* d_out, int out_size, void* d_ws,
                              size_t ws_size, hipStream_t stream) {
  const float* x = (const float*)d_in[0];
  const float* Wq = (const float*)d_in[1];
  const float* bq = (const float*)d_in[2];
  const float* Wk = (const float*)d_in[3];
  const float* bk = (const float*)d_in[4];
  const float* Wv = (const float*)d_in[5];
  const float* bv = (const float*)d_in[6];
  const float* Wp = (const float*)d_in[7];
  const float* bp = (const float*)d_in[8];
  float* out = (float*)d_out;

  __hip_bfloat16* ws = (__hip_bfloat16*)d_ws;
  __hip_bfloat16* xb = ws;                   // 8388608
  __hip_bfloat16* wqb = xb + 8388608;        // 4 x 1048576, contiguous
  __hip_bfloat16* wpb = wqb + 3 * 1048576;
  __hip_bfloat16* Qs = wqb + 4 * 1048576;    // 8388608
  __hip_bfloat16* Ks = Qs + 8388608;
  __hip_bfloat16* Vts = Ks + 8388608;        // V^T: [B*H*64][2048]
  __hip_bfloat16* Ys = Vts + 8388608;        // attn out [B*T][C]

  cvt_kernel<<<4096, 256, 0, stream>>>(x, xb, 1048576);
  cvt4_kernel<<<2048, 256, 0, stream>>>(Wq, Wk, Wv, Wp, wqb);

  gemm128<0><<<dim3(1536), 256, 0, stream>>>(xb, wqb, bq, bk, bv, Qs, Ks, Vts);

  attn_fwd<<<dim3(2048), 256, 0, stream>>>(Qs, Ks, Vts, Ys);

  gemm128<1><<<dim3(512), 256, 0, stream>>>(Ys, wpb, bp, nullptr, nullptr, out,
                                            nullptr, nullptr);
}